// Round 8
// baseline (1544.636 us; speedup 1.0000x reference)
//
#include <hip/hip_runtime.h>
#include <hip/hip_bf16.h>
#include <stdint.h>

#define N_T   1024
#define ROLLC 511
#define KCH   8
#define KN_LEV 48                 // knuth chain depth cap
#define RJ_LEV 24                 // rejection chain depth (T ~ 9-14)
#define CH_N  (2*KN_LEV + 4*RJ_LEV)

__device__ double   g_inp[N_T];
__device__ double   g_conv2[N_T];
__device__ double   g_area;
__device__ uint32_t g_chains[CH_N];
__device__ int      g_T;
__device__ float    g_ll5, g_aa5, g_bb5, g_inva5, g_vr5;   // rejection constants for lam=1e5

struct TF2 { uint32_t x, y; };

// Threefry-2x32, 20 rounds — matches jax._src.prng.threefry2x32 exactly.
__device__ __forceinline__ TF2 tf2x32(uint32_t k0, uint32_t k1, uint32_t c0, uint32_t c1) {
  uint32_t ks2 = k0 ^ k1 ^ 0x1BD11BDAu;
  uint32_t x0 = c0 + k0, x1 = c1 + k1;
#define TFR(r) { x0 += x1; x1 = (x1 << (r)) | (x1 >> (32 - (r))); x1 ^= x0; }
  TFR(13) TFR(15) TFR(26) TFR(6)
  x0 += k1;  x1 += ks2 + 1u;
  TFR(17) TFR(29) TFR(16) TFR(24)
  x0 += ks2; x1 += k0 + 2u;
  TFR(13) TFR(15) TFR(26) TFR(6)
  x0 += k0;  x1 += k1 + 3u;
  TFR(17) TFR(29) TFR(16) TFR(24)
  x0 += k1;  x1 += ks2 + 4u;
  TFR(13) TFR(15) TFR(26) TFR(6)
  x0 += ks2; x1 += k0 + 5u;
#undef TFR
  return {x0, x1};
}

// 4 independent threefry chains, manually interleaved round-by-round (in-lane ILP).
__device__ __forceinline__ void u01x4(uint32_t k0, uint32_t k1,
                                      const uint32_t m[4], float u[4]) {
  const uint32_t ks2 = k0 ^ k1 ^ 0x1BD11BDAu;
  uint32_t x0[4], x1[4];
#pragma unroll
  for (int q = 0; q < 4; ++q) { x0[q] = k0; x1[q] = m[q] + k1; }
#define RR(r) { _Pragma("unroll") for (int q = 0; q < 4; ++q) { \
    x0[q] += x1[q]; x1[q] = (x1[q] << (r)) | (x1[q] >> (32 - (r))); x1[q] ^= x0[q]; } }
#define KI(a_, b_) { _Pragma("unroll") for (int q = 0; q < 4; ++q) { x0[q] += (a_); x1[q] += (b_); } }
  RR(13) RR(15) RR(26) RR(6)
  KI(k1, ks2 + 1u)
  RR(17) RR(29) RR(16) RR(24)
  KI(ks2, k0 + 2u)
  RR(13) RR(15) RR(26) RR(6)
  KI(k0, k1 + 3u)
  RR(17) RR(29) RR(16) RR(24)
  KI(k1, ks2 + 4u)
  RR(13) RR(15) RR(26) RR(6)
  KI(ks2, k0 + 5u)
#undef RR
#undef KI
#pragma unroll
  for (int q = 0; q < 4; ++q)
    u[q] = __uint_as_float((((x0[q] ^ x1[q]) >> 9) | 0x3f800000u)) - 1.0f;
}

__device__ __forceinline__ float u01_from_key(uint32_t sk0, uint32_t sk1, uint32_t m) {
  TF2 r = tf2x32(sk0, sk1, 0u, m);
  uint32_t bits = r.x ^ r.y;
  return __uint_as_float((bits >> 9) | 0x3f800000u) - 1.0f;
}

// XLA chlo.lgamma f32 decomposition (Lanczos g=7, n=9), x >= 0.5 path only.
__device__ __forceinline__ float lgamma_xla(float x) {
#pragma clang fp contract(off)
  float z = x - 1.0f;
  float sum = 1.0f;
  sum = sum + 676.5203681218851f     / (z + 1.0f);
  sum = sum + -1259.1392167224028f   / (z + 2.0f);
  sum = sum + 771.32342877765313f    / (z + 3.0f);
  sum = sum + -176.61502916214059f   / (z + 4.0f);
  sum = sum + 12.507343278686905f    / (z + 5.0f);
  sum = sum + -0.13857109526572012f  / (z + 6.0f);
  sum = sum + 9.9843695780195716e-6f / (z + 7.0f);
  sum = sum + 1.5056327351493116e-7f / (z + 8.0f);
  float t = 7.5f + z;
  float log_t = 2.0149030205422647f + log1pf(z / 7.5f);
  return 0.91893853320467274f + (z + 0.5f - t / log_t) * log_t + logf(sum);
}

__device__ __forceinline__ void rej_constants(float lam, float* ll, float* aa, float* bb,
                                              float* inva, float* vr) {
#pragma clang fp contract(off)
  *ll = logf(lam);
  float b = 0.931f + 2.53f * sqrtf(lam);
  float a = -0.059f + 0.02483f * b;
  *bb = b; *aa = a;
  *inva = 1.1239f + 1.1328f / (b - 3.4f);
  *vr = 0.9277f - 3.6224f / (b - 2.0f);
}

// Quick classification: 1 = accept, -1 = definite reject, 0 = ambiguous.
__device__ __forceinline__ int ptrs_quick(float lamr, float aa, float bb, float vr,
                                          float u, float v) {
#pragma clang fp contract(off)
  float us = 0.5f - fabsf(u);
  float kf = floorf((2.0f * aa / us + bb) * u + lamr + 0.43f);
  if ((us >= 0.07f) && (v <= vr)) return 1;
  if ((kf < 0.0f) || ((us < 0.013f) && (v > us))) return -1;
  return 0;
}

// Slow (exact) accept test for ambiguous cases.
__device__ __forceinline__ bool ptrs_slow(float lamr, float ll, float aa, float bb,
                                          float inva, float u, float v) {
#pragma clang fp contract(off)
  float us = 0.5f - fabsf(u);
  float kf = floorf((2.0f * aa / us + bb) * u + lamr + 0.43f);
  float s = logf(v * inva / (aa / (us * us) + bb));
  float t = (-lamr + kf * ll) - lgamma_xla(kf + 1.0f);
  return s <= t;
}

// One full Hormann PTRS iteration (exact).
__device__ __forceinline__ bool rej_iter(float lam, float ll, float aa, float bb,
                                         float inva, float vr, float u, float v, float* kf) {
#pragma clang fp contract(off)
  float us = 0.5f - fabsf(u);
  float k = floorf((2.0f * aa / us + bb) * u + lam + 0.43f);
  *kf = k;
  if ((us >= 0.07f) && (v <= vr)) return true;
  if ((k < 0.0f) || ((us < 0.013f) && (v > us))) return false;
  float s = logf(v * inva / (aa / (us * us) + bb));
  float t = (-lam + k * ll) - lgamma_xla(k + 1.0f);
  return s <= t;
}

// Backward-from-T scan: last accept in 1..T == first accept scanning T-1..0.
__device__ __forceinline__ float rej_backward(float lam, uint32_t m, int T) {
  float ll, aa, bbv, inva, vr;
  rej_constants(lam, &ll, &aa, &bbv, &inva, &vr);
  float kout = -1.0f;
  bool found = false;
#pragma unroll 1
  for (int jj = T - 1; jj >= 0 && !found; jj -= 4) {
    float kf0, kf1, kf2, kf3;
    bool a0 = false, a1 = false, a2 = false, a3 = false;
    {
      const uint32_t* c = g_chains + 2*KN_LEV + 4*jj;
      a0 = rej_iter(lam, ll, aa, bbv, inva, vr,
                    u01_from_key(c[0], c[1], m) - 0.5f, u01_from_key(c[2], c[3], m), &kf0);
    }
    if (jj - 1 >= 0) {
      const uint32_t* c = g_chains + 2*KN_LEV + 4*(jj-1);
      a1 = rej_iter(lam, ll, aa, bbv, inva, vr,
                    u01_from_key(c[0], c[1], m) - 0.5f, u01_from_key(c[2], c[3], m), &kf1);
    }
    if (jj - 2 >= 0) {
      const uint32_t* c = g_chains + 2*KN_LEV + 4*(jj-2);
      a2 = rej_iter(lam, ll, aa, bbv, inva, vr,
                    u01_from_key(c[0], c[1], m) - 0.5f, u01_from_key(c[2], c[3], m), &kf2);
    }
    if (jj - 3 >= 0) {
      const uint32_t* c = g_chains + 2*KN_LEV + 4*(jj-3);
      a3 = rej_iter(lam, ll, aa, bbv, inva, vr,
                    u01_from_key(c[0], c[1], m) - 0.5f, u01_from_key(c[2], c[3], m), &kf3);
    }
    if      (a0) { kout = kf0; found = true; }
    else if (a1) { kout = kf1; found = true; }
    else if (a2) { kout = kf2; found = true; }
    else if (a3) { kout = kf3; found = true; }
  }
  return kout;
}

// pre1: first f64 circular conv (+roll) of relu(illum) with irf -> g_inp. 8 blocks x 128.
__global__ void __launch_bounds__(128)
pre1_kernel(const float* __restrict__ illum, const float* __restrict__ irf) {
  __shared__ double xs[N_T], irfs[N_T];
  const int tid = threadIdx.x;
  for (int i = tid; i < N_T; i += 128) {
    xs[i]   = fmax((double)illum[i], 0.0);
    irfs[i] = (double)irf[i];
  }
  __syncthreads();
  const int t  = blockIdx.x * 128 + tid;
  const int tt = (t + ROLLC) & (N_T - 1);
  double acc = 0.0;
  for (int j = 0; j < N_T; ++j) acc += xs[j] * irfs[(tt - j) & (N_T - 1)];
  g_inp[t] = acc;
}

// pre2: blocks 0-7 second conv (+roll) -> g_conv2; block 8: area, chains, constants, resets.
__global__ void __launch_bounds__(128)
pre2_kernel(const float* __restrict__ irf, uint32_t* __restrict__ hdr) {
  __shared__ double inps[N_T], irfs[N_T];
  const int tid = threadIdx.x;
  if (blockIdx.x < 8) {
    for (int i = tid; i < N_T; i += 128) {
      inps[i] = g_inp[i];
      irfs[i] = (double)irf[i];
    }
    __syncthreads();
    const int t  = blockIdx.x * 128 + tid;
    const int tt = (t + ROLLC) & (N_T - 1);
    double acc = 0.0;
    for (int j = 0; j < N_T; ++j) acc += inps[j] * irfs[(tt - j) & (N_T - 1)];
    g_conv2[t] = acc;
  } else {
    if (tid == 0) {
      g_T = 1;
      hdr[0] = 0u; hdr[1] = 0u; hdr[2] = 0u;
      double area = 0.0;
      for (int j = 0; j < N_T; ++j) area += g_inp[j];
      g_area = area;
    } else if (tid == 1) {
      uint32_t r0 = 0u, r1 = 42u;           // knuth chain: rng,sub = split(rng)
      for (int j = 0; j < KN_LEV; ++j) {
        TF2 sub = tf2x32(r0, r1, 0u, 1u);
        TF2 nxt = tf2x32(r0, r1, 0u, 0u);
        g_chains[2*j] = sub.x; g_chains[2*j+1] = sub.y;
        r0 = nxt.x; r1 = nxt.y;
      }
    } else if (tid == 2) {
      uint32_t c0 = 0u, c1 = 42u;           // rejection chain: split(key,3)
      for (int j = 0; j < RJ_LEV; ++j) {
        TF2 nxt = tf2x32(c0, c1, 0u, 0u);
        TF2 s0  = tf2x32(c0, c1, 0u, 1u);
        TF2 s1  = tf2x32(c0, c1, 0u, 2u);
        int base = 2*KN_LEV + 4*j;
        g_chains[base]   = s0.x; g_chains[base+1] = s0.y;
        g_chains[base+2] = s1.x; g_chains[base+3] = s1.y;
        c0 = nxt.x; c1 = nxt.y;
      }
    } else if (tid == 3) {
      float ll, aa, bb, inva, vr;
      rej_constants(1e5f, &ll, &aa, &bb, &inva, &vr);
      g_ll5 = ll; g_aa5 = aa; g_bb5 = bb; g_inva5 = inva; g_vr5 = vr;
    }
  }
}

// kA: 4 elements per lane, all threefry work 4-way interleaved (in-lane ILP).
// Does: lam, L1 T-eval, dense knuth + tail, einsum for knuth elems, survivor
// flush and rejection-element list (one atomic each per block).
__global__ void __launch_bounds__(256, 4)
kA_kernel(const float* __restrict__ photon, const float* __restrict__ sbr,
          const int* __restrict__ bins, const float* __restrict__ w,
          float* __restrict__ out, uint32_t* __restrict__ hdr,
          uint2* __restrict__ recs, uint32_t capS, uint32_t rmax) {
  __shared__ uint32_t ch[CH_N];
  __shared__ uint2    sstage[N_T];          // T-survivor staging (per-wave 256 segs)
  __shared__ uint2    rstage[N_T];          // rejection-element staging
  __shared__ uint16_t tpk[N_T];             // knuth tail staging (k<<10|t)
  __shared__ float    tlp[N_T];
  __shared__ uint32_t scnts[4], rcnts[4];
  __shared__ uint32_t sbase, rbase;
  __shared__ float    wred[4][KCH];
  const int b = blockIdx.x, tid = threadIdx.x;
  const int wv = tid >> 6, lane = tid & 63;
  for (int i = tid; i < CH_N; i += 256) ch[i] = g_chains[i];
  __syncthreads();

  const float  ph = photon[b], sb = sbr[b];
  const int    shift = bins[b] & (N_T - 1);
  const double scale = (double)ph / g_area;
  const float  r1f = ph / sb;
  const double amb = (double)r1f * (1.0 / 1024.0);
  const uint32_t mbase = (uint32_t)b << 10;
  const uint32_t ka0 = ch[2*KN_LEV+0], ka1 = ch[2*KN_LEV+1];
  const uint32_t kc0 = ch[2*KN_LEV+2], kc1 = ch[2*KN_LEV+3];
  const float ll5 = g_ll5, aa5 = g_aa5, bb5 = g_bb5, inva5 = g_inva5, vr5 = g_vr5;
  const unsigned long long lmask = (1ull << lane) - 1ull;

  uint32_t m4[4]; float lam4[4]; float neg4[4]; bool isR[4];
  float glam = 0.0f;
#pragma unroll
  for (int q = 0; q < 4; ++q) {
    const int t   = (wv << 8) + (q << 6) + lane;
    const int src = (t - shift) & (N_T - 1);
    const float lam = (float)(scale * g_conv2[src] + amb);
    lam4[q] = lam; m4[q] = mbase + (uint32_t)t;
    isR[q]  = (lam >= 10.0f);
    neg4[q] = isR[q] ? 1.0f : -lam;
    glam = fmaxf(glam, isR[q] ? 0.0f : lam);
  }

  // ---- L1 of the T-chain (dense, 4-way interleaved)
  float u4[4], v4[4];
  u01x4(ka0, ka1, m4, u4);
  u01x4(kc0, kc1, m4, v4);

  uint32_t wcS = 0, wcR = 0, wcT = 0;
#pragma unroll
  for (int q = 0; q < 4; ++q) {
    const float lamr = isR[q] ? lam4[q] : 1e5f;
    const float u = u4[q] - 0.5f, v = v4[q];
    float bbq, aaq, vrq;
    {
#pragma clang fp contract(off)
      float b2 = 0.931f + 2.53f * sqrtf(lamr);
      float aq = -0.059f + 0.02483f * b2;
      float vq = 0.9277f - 3.6224f / (b2 - 2.0f);
      bbq = isR[q] ? b2 : bb5;
      aaq = isR[q] ? aq : aa5;
      vrq = isR[q] ? vq : vr5;
    }
    int cls = ptrs_quick(lamr, aaq, bbq, vrq, u, v);
    bool surv;
    if (cls == 0) {
      float ll = isR[q] ? logf(lamr) : ll5;
      float inva;
      {
#pragma clang fp contract(off)
        inva = isR[q] ? (1.1239f + 1.1328f / (bbq - 3.4f)) : inva5;
      }
      surv = !ptrs_slow(lamr, ll, aaq, bbq, inva, u, v);
    } else {
      surv = (cls < 0);
    }
    {
      unsigned long long vote = __ballot(surv);
      uint32_t slot = wcS + (uint32_t)__popcll(vote & lmask);
      if (surv) sstage[(wv << 8) + slot] = make_uint2(m4[q], __float_as_uint(lamr));
      wcS += (uint32_t)__popcll(vote);
    }
    {
      unsigned long long vote = __ballot(isR[q]);
      uint32_t slot = wcR + (uint32_t)__popcll(vote & lmask);
      if (isR[q]) rstage[(wv << 8) + slot] = make_uint2(m4[q], __float_as_uint(lam4[q]));
      wcR += (uint32_t)__popcll(vote);
    }
  }

  // ---- dense knuth, wave-uniform depth, 4-way interleaved threefry per level
#pragma unroll
  for (int off = 32; off > 0; off >>= 1) glam = fmaxf(glam, __shfl_xor(glam, off, 64));
  int D = 0;
  if (glam > 0.0f) {
    D = (int)(glam + 2.0f * sqrtf(glam)) + 2;
    if (D > KN_LEV) D = KN_LEV;
  }
  float lp4[4] = {0.0f, 0.0f, 0.0f, 0.0f};
  int   k4[4]  = {0, 0, 0, 0};
#pragma unroll 1
  for (int j = 0; j < D; ++j) {
    const uint32_t kk0 = ch[2*j], kk1 = ch[2*j+1];
    u01x4(kk0, kk1, m4, u4);
#pragma unroll
    for (int q = 0; q < 4; ++q) {
      k4[q] += (lp4[q] > neg4[q]) ? 1 : 0;
      lp4[q] += __logf(u4[q]);
    }
  }

  float acc[KCH];
#pragma unroll
  for (int k = 0; k < KCH; ++k) acc[k] = 0.0f;
#pragma unroll
  for (int q = 0; q < 4; ++q) {
    const bool kn = !isR[q];
    const bool alive = kn && (lp4[q] > neg4[q]);   // survivors have k == D
    const float cntf = (kn && !alive) ? (float)(k4[q] - 1) : 0.0f;
    const int t = (wv << 8) + (q << 6) + lane;
#pragma unroll
    for (int kk = 0; kk < KCH; ++kk) acc[kk] += cntf * w[kk * N_T + t];
    unsigned long long vote = __ballot(alive);
    uint32_t slot = wcT + (uint32_t)__popcll(vote & lmask);
    if (alive) { tpk[(wv << 8) + slot] = (uint16_t)(((uint32_t)k4[q] << 10) | (uint32_t)t);
                 tlp[(wv << 8) + slot] = lp4[q]; }
    wcT += (uint32_t)__popcll(vote);
  }

  // ---- knuth tail (per-wave compacted, ~1-3% of elements)
  for (uint32_t i = lane; i < wcT; i += 64) {
    const uint32_t pk = tpk[(wv << 8) + i];
    const uint32_t t  = pk & 1023u;
    int k = (int)(pk >> 10);
    float lp = tlp[(wv << 8) + i];
    const int src = ((int)t - shift) & (N_T - 1);
    const float lam = (float)(scale * g_conv2[src] + amb);
    const float neg = -lam;
    const uint32_t m = mbase + t;
    int j = k;                              // levels consumed == k for survivors
#pragma unroll 1
    while ((lp > neg) && (j < KN_LEV)) {
      ++k;
      lp += __logf(u01_from_key(ch[2*j], ch[2*j+1], m));
      ++j;
    }
    const float cntf = (float)(k - 1);
#pragma unroll
    for (int kk = 0; kk < KCH; ++kk) acc[kk] += cntf * w[kk * N_T + t];
  }

  // ---- block einsum reduce + flushes (ONE global atomic per list per block)
#pragma unroll
  for (int kk = 0; kk < KCH; ++kk) {
    float vv = acc[kk];
    for (int off = 32; off > 0; off >>= 1) vv += __shfl_down(vv, off, 64);
    if (lane == 0) wred[wv][kk] = vv;
  }
  if (lane == 0) { scnts[wv] = wcS; rcnts[wv] = wcR; }
  __syncthreads();
  if (tid == 0) sbase = atomicAdd(&hdr[0], scnts[0] + scnts[1] + scnts[2] + scnts[3]);
  if (tid == 1) rbase = atomicAdd(&hdr[1], rcnts[0] + rcnts[1] + rcnts[2] + rcnts[3]);
  if (tid < KCH)
    out[b * KCH + tid] = wred[0][tid] + wred[1][tid] + wred[2][tid] + wred[3][tid];
  __syncthreads();
  uint32_t preS = 0, preR = 0;
  for (int ww = 0; ww < wv; ++ww) { preS += scnts[ww]; preR += rcnts[ww]; }
  const uint32_t baseS = sbase + preS;
  for (uint32_t i = lane; i < wcS; i += 64) {
    const uint32_t g = baseS + i;
    const uint2 r = sstage[(wv << 8) + i];
    if (g < capS) {
      recs[g] = r;
    } else {  // ws overflow: resolve T contribution exactly inline
      const uint32_t m = r.x; const float lamr = __uint_as_float(r.y);
      float ll, aaf, bbf, invaf, vrf;
      if (lamr == 1e5f) { ll = ll5; aaf = aa5; bbf = bb5; invaf = inva5; vrf = vr5; }
      else rej_constants(lamr, &ll, &aaf, &bbf, &invaf, &vrf);
      int jf = RJ_LEV;
#pragma unroll 1
      for (int j = 1; j < RJ_LEV; ++j) {
        float uu = u01_from_key(ch[2*KN_LEV + 4*j], ch[2*KN_LEV + 4*j + 1], m) - 0.5f;
        float vv = u01_from_key(ch[2*KN_LEV + 4*j + 2], ch[2*KN_LEV + 4*j + 3], m);
        float kk;
        if (rej_iter(lamr, ll, aaf, bbf, invaf, vrf, uu, vv, &kk)) { jf = j + 1; break; }
      }
      atomicMax(&g_T, jf);
    }
  }
  const uint32_t baseR = rbase + preR;
  for (uint32_t i = lane; i < wcR; i += 64) {
    const uint32_t g = baseR + i;
    if (g < rmax) recs[capS + g] = rstage[(wv << 8) + i];
    else hdr[2] = 1u;                       // overflow -> kB full-rewalk fallback
  }
}

// t2: levels 2+ for compacted T-survivors only; global T via atomicMax.
__global__ void __launch_bounds__(256)
t2_kernel(const uint32_t* __restrict__ hdr, const uint2* __restrict__ recs, uint32_t capS) {
  __shared__ uint32_t chs[4*RJ_LEV];
  __shared__ int bmax;
  const int tid = threadIdx.x;
  if (tid < 4*RJ_LEV) chs[tid] = g_chains[2*KN_LEV + tid];
  if (tid == 0) bmax = 1;
  __syncthreads();
  uint32_t n = hdr[0]; if (n > capS) n = capS;
  const float ll5 = g_ll5, aa5 = g_aa5, bb5 = g_bb5, inva5 = g_inva5, vr5 = g_vr5;
  int mymax = 1;
  for (uint32_t gi = blockIdx.x * 256u + tid; gi < n; gi += gridDim.x * 256u) {
    uint2 r = recs[gi];
    const uint32_t m = r.x; const float lamr = __uint_as_float(r.y);
    float ll, aa, bbv, inva, vr;
    if (lamr == 1e5f) { ll = ll5; aa = aa5; bbv = bb5; inva = inva5; vr = vr5; }
    else rej_constants(lamr, &ll, &aa, &bbv, &inva, &vr);
    int jf = RJ_LEV;
#pragma unroll 1
    for (int j = 1; j < RJ_LEV; ++j) {
      float uu = u01_from_key(chs[4*j], chs[4*j+1], m) - 0.5f;
      float vv = u01_from_key(chs[4*j+2], chs[4*j+3], m);
      float kk;
      if (rej_iter(lamr, ll, aa, bbv, inva, vr, uu, vv, &kk)) { jf = j + 1; break; }
    }
    mymax = max(mymax, jf);
  }
  for (int off = 32; off > 0; off >>= 1) mymax = max(mymax, __shfl_down(mymax, off, 64));
  if ((tid & 63) == 0) atomicMax(&bmax, mymax);
  __syncthreads();
  if (tid == 0) atomicMax(&g_T, bmax);
}

// kB: backward-from-T rejection for the COMPACTED rejection list (~0.5-4% of elems);
// full-rewalk only if the list overflowed ws.
__global__ void __launch_bounds__(256)
kB_kernel(const float* __restrict__ photon, const float* __restrict__ sbr,
          const int* __restrict__ bins, const float* __restrict__ w,
          float* __restrict__ out, const uint32_t* __restrict__ hdr,
          const uint2* __restrict__ recs, uint32_t capS, uint32_t rmax, int B) {
  const int tid = threadIdx.x;
  const int T = g_T;
  if (hdr[2] == 0u) {
    uint32_t n = hdr[1]; if (n > rmax) n = rmax;
    for (uint32_t gi = blockIdx.x * 256u + tid; gi < n; gi += gridDim.x * 256u) {
      const uint2 r = recs[capS + gi];
      const uint32_t m = r.x; const float lam = __uint_as_float(r.y);
      const float kout = rej_backward(lam, m, T);
      const uint32_t bb_ = m >> 10, tt_ = m & 1023u;
#pragma unroll
      for (int kk = 0; kk < KCH; ++kk)
        atomicAdd(&out[bb_ * KCH + kk], kout * w[kk * N_T + tt_]);
    }
  } else {
    const uint32_t total = (uint32_t)B << 10;
    for (uint32_t gi = blockIdx.x * 256u + tid; gi < total; gi += gridDim.x * 256u) {
      const uint32_t bb_ = gi >> 10, tt_ = gi & 1023u;
      const float ph = photon[bb_], sbv = sbr[bb_];
      const int shift = bins[bb_] & (N_T - 1);
      const double scale = (double)ph / g_area;
      const float r1f = ph / sbv;
      const double amb = (double)r1f * (1.0 / 1024.0);
      const int src = ((int)tt_ - shift) & (N_T - 1);
      const float lam = (float)(scale * g_conv2[src] + amb);
      if (lam >= 10.0f) {
        const uint32_t m = (bb_ << 10) + tt_;
        const float kout = rej_backward(lam, m, T);
#pragma unroll
        for (int kk = 0; kk < KCH; ++kk)
          atomicAdd(&out[bb_ * KCH + kk], kout * w[kk * N_T + tt_]);
      }
    }
  }
}

extern "C" void kernel_launch(void* const* d_in, const int* in_sizes, int n_in,
                              void* d_out, int out_size, void* d_ws, size_t ws_size,
                              hipStream_t stream) {
  (void)n_in; (void)out_size;
  const float* illum  = (const float*)d_in[0];
  const float* photon = (const float*)d_in[1];
  const float* sbr    = (const float*)d_in[2];
  const float* irf    = (const float*)d_in[3];
  const float* w      = (const float*)d_in[4];
  const int*   bins   = (const int*)d_in[5];
  float* out = (float*)d_out;
  const int B = in_sizes[1];

  uint32_t* hdr = (uint32_t*)d_ws;
  uint2*    recs = (uint2*)((char*)d_ws + 16);
  uint32_t  capTot = (ws_size > 16) ? (uint32_t)((ws_size - 16) / sizeof(uint2)) : 0u;
  uint32_t  rmax = capTot / 4; if (rmax > 4194304u) rmax = 4194304u;
  uint32_t  capS = capTot - rmax;

  pre1_kernel<<<8, 128, 0, stream>>>(illum, irf);
  pre2_kernel<<<9, 128, 0, stream>>>(irf, hdr);
  kA_kernel<<<B, 256, 0, stream>>>(photon, sbr, bins, w, out, hdr, recs, capS, rmax);
  t2_kernel<<<2048, 256, 0, stream>>>(hdr, recs, capS);
  kB_kernel<<<1024, 256, 0, stream>>>(photon, sbr, bins, w, out, hdr, recs, capS, rmax, B);
}

// Round 9
// 1261.733 us; speedup vs baseline: 1.2242x; 1.2242x over previous
//
#include <hip/hip_runtime.h>
#include <hip/hip_bf16.h>
#include <stdint.h>

#define N_T   1024
#define ROLLC 511
#define KCH   8
#define KN_LEV 48                 // knuth chain depth cap
#define DENSE_L 3                 // branch-free dense knuth levels (phase 1)
#define RJ_LEV 24                 // rejection chain depth (T ~ 9-14)
#define CH_N  (2*KN_LEV + 4*RJ_LEV)

__device__ double   g_inp[N_T];
__device__ double   g_conv2[N_T];
__device__ double   g_area;
__device__ uint32_t g_chains[CH_N];
__device__ int      g_T;
__device__ float    g_ll5, g_aa5, g_bb5, g_inva5, g_vr5;   // rejection constants for lam=1e5

struct TF2 { uint32_t x, y; };

// Threefry-2x32, 20 rounds — matches jax._src.prng.threefry2x32 exactly.
__device__ __forceinline__ TF2 tf2x32(uint32_t k0, uint32_t k1, uint32_t c0, uint32_t c1) {
  uint32_t ks2 = k0 ^ k1 ^ 0x1BD11BDAu;
  uint32_t x0 = c0 + k0, x1 = c1 + k1;
#define TFR(r) { x0 += x1; x1 = (x1 << (r)) | (x1 >> (32 - (r))); x1 ^= x0; }
  TFR(13) TFR(15) TFR(26) TFR(6)
  x0 += k1;  x1 += ks2 + 1u;
  TFR(17) TFR(29) TFR(16) TFR(24)
  x0 += ks2; x1 += k0 + 2u;
  TFR(13) TFR(15) TFR(26) TFR(6)
  x0 += k0;  x1 += k1 + 3u;
  TFR(17) TFR(29) TFR(16) TFR(24)
  x0 += k1;  x1 += ks2 + 4u;
  TFR(13) TFR(15) TFR(26) TFR(6)
  x0 += ks2; x1 += k0 + 5u;
#undef TFR
  return {x0, x1};
}

__device__ __forceinline__ float u01_from_key(uint32_t sk0, uint32_t sk1, uint32_t m) {
  TF2 r = tf2x32(sk0, sk1, 0u, m);
  uint32_t bits = r.x ^ r.y;
  return __uint_as_float((bits >> 9) | 0x3f800000u) - 1.0f;
}

// XLA chlo.lgamma f32 decomposition (Lanczos g=7, n=9), x >= 0.5 path only.
__device__ __forceinline__ float lgamma_xla(float x) {
#pragma clang fp contract(off)
  float z = x - 1.0f;
  float sum = 1.0f;
  sum = sum + 676.5203681218851f     / (z + 1.0f);
  sum = sum + -1259.1392167224028f   / (z + 2.0f);
  sum = sum + 771.32342877765313f    / (z + 3.0f);
  sum = sum + -176.61502916214059f   / (z + 4.0f);
  sum = sum + 12.507343278686905f    / (z + 5.0f);
  sum = sum + -0.13857109526572012f  / (z + 6.0f);
  sum = sum + 9.9843695780195716e-6f / (z + 7.0f);
  sum = sum + 1.5056327351493116e-7f / (z + 8.0f);
  float t = 7.5f + z;
  float log_t = 2.0149030205422647f + log1pf(z / 7.5f);
  return 0.91893853320467274f + (z + 0.5f - t / log_t) * log_t + logf(sum);
}

__device__ __forceinline__ void rej_constants(float lam, float* ll, float* aa, float* bb,
                                              float* inva, float* vr) {
#pragma clang fp contract(off)
  *ll = logf(lam);
  float b = 0.931f + 2.53f * sqrtf(lam);
  float a = -0.059f + 0.02483f * b;
  *bb = b; *aa = a;
  *inva = 1.1239f + 1.1328f / (b - 3.4f);
  *vr = 0.9277f - 3.6224f / (b - 2.0f);
}

// Quick classification: 1 = accept, -1 = definite reject, 0 = ambiguous.
__device__ __forceinline__ int ptrs_quick(float lamr, float aa, float bb, float vr,
                                          float u, float v) {
#pragma clang fp contract(off)
  float us = 0.5f - fabsf(u);
  float kf = floorf((2.0f * aa / us + bb) * u + lamr + 0.43f);
  if ((us >= 0.07f) && (v <= vr)) return 1;
  if ((kf < 0.0f) || ((us < 0.013f) && (v > us))) return -1;
  return 0;
}

// Slow (exact) accept test for ambiguous cases.
__device__ __forceinline__ bool ptrs_slow(float lamr, float ll, float aa, float bb,
                                          float inva, float u, float v) {
#pragma clang fp contract(off)
  float us = 0.5f - fabsf(u);
  float kf = floorf((2.0f * aa / us + bb) * u + lamr + 0.43f);
  float s = logf(v * inva / (aa / (us * us) + bb));
  float t = (-lamr + kf * ll) - lgamma_xla(kf + 1.0f);
  return s <= t;
}

// One full Hormann PTRS iteration (exact).
__device__ __forceinline__ bool rej_iter(float lam, float ll, float aa, float bb,
                                         float inva, float vr, float u, float v, float* kf) {
#pragma clang fp contract(off)
  float us = 0.5f - fabsf(u);
  float k = floorf((2.0f * aa / us + bb) * u + lam + 0.43f);
  *kf = k;
  if ((us >= 0.07f) && (v <= vr)) return true;
  if ((k < 0.0f) || ((us < 0.013f) && (v > us))) return false;
  float s = logf(v * inva / (aa / (us * us) + bb));
  float t = (-lam + k * ll) - lgamma_xla(k + 1.0f);
  return s <= t;
}

// Wave-aggregated append to an LDS counter. All 64 lanes must call.
__device__ __forceinline__ uint32_t wave_append(bool pred, uint32_t* counter) {
  unsigned long long vote = __ballot(pred);
  int lane = threadIdx.x & 63;
  uint32_t base = 0;
  int cnt = __popcll(vote);
  if (cnt) {
    int leader = __ffsll((unsigned long long)vote) - 1;
    if (lane == leader) base = atomicAdd(counter, (uint32_t)cnt);
    base = (uint32_t)__shfl((int)base, leader, 64);
  }
  return base + (uint32_t)__popcll(vote & ((1ull << lane) - 1ull));
}

// pre1: first f64 circular conv (+roll) of relu(illum) with irf -> g_inp. 8 blocks x 128.
__global__ void __launch_bounds__(128)
pre1_kernel(const float* __restrict__ illum, const float* __restrict__ irf) {
  __shared__ double xs[N_T], irfs[N_T];
  const int tid = threadIdx.x;
  for (int i = tid; i < N_T; i += 128) {
    xs[i]   = fmax((double)illum[i], 0.0);
    irfs[i] = (double)irf[i];
  }
  __syncthreads();
  const int t  = blockIdx.x * 128 + tid;
  const int tt = (t + ROLLC) & (N_T - 1);
  double acc = 0.0;
  for (int j = 0; j < N_T; ++j) acc += xs[j] * irfs[(tt - j) & (N_T - 1)];
  g_inp[t] = acc;
}

// pre2: blocks 0-7 second conv (+roll) -> g_conv2; block 8: area, chains, constants, resets.
__global__ void __launch_bounds__(128)
pre2_kernel(const float* __restrict__ irf, uint32_t* __restrict__ wcount) {
  __shared__ double inps[N_T], irfs[N_T];
  const int tid = threadIdx.x;
  if (blockIdx.x < 8) {
    for (int i = tid; i < N_T; i += 128) {
      inps[i] = g_inp[i];
      irfs[i] = (double)irf[i];
    }
    __syncthreads();
    const int t  = blockIdx.x * 128 + tid;
    const int tt = (t + ROLLC) & (N_T - 1);
    double acc = 0.0;
    for (int j = 0; j < N_T; ++j) acc += inps[j] * irfs[(tt - j) & (N_T - 1)];
    g_conv2[t] = acc;
  } else {
    if (tid == 0) {
      g_T = 1;
      wcount[0] = 0u;
      double area = 0.0;
      for (int j = 0; j < N_T; ++j) area += g_inp[j];
      g_area = area;
    } else if (tid == 1) {
      uint32_t r0 = 0u, r1 = 42u;           // knuth chain: rng,sub = split(rng)
      for (int j = 0; j < KN_LEV; ++j) {
        TF2 sub = tf2x32(r0, r1, 0u, 1u);
        TF2 nxt = tf2x32(r0, r1, 0u, 0u);
        g_chains[2*j] = sub.x; g_chains[2*j+1] = sub.y;
        r0 = nxt.x; r1 = nxt.y;
      }
    } else if (tid == 2) {
      uint32_t c0 = 0u, c1 = 42u;           // rejection chain: split(key,3)
      for (int j = 0; j < RJ_LEV; ++j) {
        TF2 nxt = tf2x32(c0, c1, 0u, 0u);
        TF2 s0  = tf2x32(c0, c1, 0u, 1u);
        TF2 s1  = tf2x32(c0, c1, 0u, 2u);
        int base = 2*KN_LEV + 4*j;
        g_chains[base]   = s0.x; g_chains[base+1] = s0.y;
        g_chains[base+2] = s1.x; g_chains[base+3] = s1.y;
        c0 = nxt.x; c1 = nxt.y;
      }
    } else if (tid == 3) {
      float ll, aa, bb, inva, vr;
      rej_constants(1e5f, &ll, &aa, &bb, &inva, &vr);
      g_ll5 = ll; g_aa5 = aa; g_bb5 = bb; g_inva5 = inva; g_vr5 = vr;
    }
  }
}

// t1 (r6 structure, best measured): dense quick-classify; ambiguous compacted in LDS
// + slow eval; survivors staged in LDS; ONE global atomicAdd per block; coalesced flush.
__global__ void __launch_bounds__(256)
t1_kernel(const float* __restrict__ photon, const float* __restrict__ sbr,
          const int* __restrict__ bins, uint32_t* __restrict__ wcount,
          uint2* __restrict__ recs, uint32_t cap) {
  __shared__ uint2    lrec[N_T];                   // survivors (8KB)
  __shared__ uint32_t amb_m[N_T];                  // ambiguous (4KB)
  __shared__ float    amb_u[N_T], amb_v[N_T], amb_lam[N_T];  // (12KB)
  __shared__ uint32_t lcount, acount, gbase;
  const int b = blockIdx.x, tid = threadIdx.x;
  if (tid == 0) { lcount = 0u; acount = 0u; }
  __syncthreads();

  const float ph = photon[b], sb = sbr[b];
  const int   shift = bins[b] & (N_T - 1);
  const double scale = (double)ph / g_area;
  const float  r1f = ph / sb;
  const double amb = (double)r1f * (1.0 / 1024.0);
  const uint32_t sa0 = g_chains[2*KN_LEV+0], sa1 = g_chains[2*KN_LEV+1];
  const uint32_t sc0 = g_chains[2*KN_LEV+2], sc1 = g_chains[2*KN_LEV+3];
  const float ll5 = g_ll5, aa5 = g_aa5, bb5 = g_bb5, inva5 = g_inva5, vr5 = g_vr5;
  const uint32_t mbase = (uint32_t)b << 10;

  // dense quick classification
  for (int i2 = 0; i2 < 4; ++i2) {
    const int t   = tid + (i2 << 8);
    const int src = (t - shift) & (N_T - 1);
    const float lam = (float)(scale * g_conv2[src] + amb);
    float lamr, aa, bbv, vr;
    if (lam < 10.0f) { lamr = 1e5f; aa = aa5; bbv = bb5; vr = vr5; }
    else {
#pragma clang fp contract(off)
      lamr = lam;
      float b2 = 0.931f + 2.53f * sqrtf(lam);
      bbv = b2; aa = -0.059f + 0.02483f * b2;
      vr = 0.9277f - 3.6224f / (b2 - 2.0f);
    }
    const uint32_t m = mbase + (uint32_t)t;
    float u = u01_from_key(sa0, sa1, m) - 0.5f;
    float v = u01_from_key(sc0, sc1, m);
    int cls = ptrs_quick(lamr, aa, bbv, vr, u, v);
    bool surv = (cls < 0);
    bool ambg = (cls == 0);
    uint32_t sS = wave_append(surv, &lcount);
    if (surv) lrec[sS] = make_uint2(m, __float_as_uint(lamr));
    uint32_t sA = wave_append(ambg, &acount);
    if (ambg) { amb_m[sA] = m; amb_u[sA] = u; amb_v[sA] = v; amb_lam[sA] = lamr; }
  }
  __syncthreads();

  // compacted slow eval (exact) for ambiguous
  const uint32_t na = acount;
  const uint32_t naPad = (na + 255u) & ~255u;
  for (uint32_t i = tid; i < naPad; i += 256) {
    bool active = (i < na);
    bool surv = false;
    uint32_t m = 0; float lamr = 0.f;
    if (active) {
      m = amb_m[i]; lamr = amb_lam[i];
      float u = amb_u[i], v = amb_v[i];
      float ll, aa, bbv, inva;
      if (lamr == 1e5f) { ll = ll5; aa = aa5; bbv = bb5; inva = inva5; }
      else {
#pragma clang fp contract(off)
        float b2 = 0.931f + 2.53f * sqrtf(lamr);
        bbv = b2; aa = -0.059f + 0.02483f * b2;
        ll = logf(lamr);
        inva = 1.1239f + 1.1328f / (b2 - 3.4f);
      }
      surv = !ptrs_slow(lamr, ll, aa, bbv, inva, u, v);
    }
    uint32_t sS = wave_append(surv, &lcount);
    if (surv) lrec[sS] = make_uint2(m, __float_as_uint(lamr));
  }
  __syncthreads();

  // ONE global atomic per block, then coalesced flush
  if (tid == 0) gbase = atomicAdd(wcount, lcount);
  __syncthreads();
  const uint32_t lc = lcount, base = gbase;
  for (uint32_t i = tid; i < lc; i += 256) {
    const uint32_t g = base + i;
    uint2 r = lrec[i];
    if (g < cap) {
      recs[g] = r;
    } else {  // ws overflow (not expected): resolve exactly inline
      const uint32_t m = r.x; const float lamr = __uint_as_float(r.y);
      float ll, aaf, bbf, invaf, vrf;
      if (lamr == 1e5f) { ll = ll5; aaf = aa5; bbf = bb5; invaf = inva5; vrf = vr5; }
      else rej_constants(lamr, &ll, &aaf, &bbf, &invaf, &vrf);
      int jf = RJ_LEV;
#pragma unroll 1
      for (int j = 1; j < RJ_LEV; ++j) {
        const uint32_t* c = g_chains + 2*KN_LEV + 4*j;
        float uu = u01_from_key(c[0], c[1], m) - 0.5f;
        float vv = u01_from_key(c[2], c[3], m);
        float kk;
        if (rej_iter(lamr, ll, aaf, bbf, invaf, vrf, uu, vv, &kk)) { jf = j + 1; break; }
      }
      atomicMax(&g_T, jf);
    }
  }
}

// t2: levels 2+ for compacted survivors only; global T via atomicMax.
__global__ void __launch_bounds__(256)
t2_kernel(const uint32_t* __restrict__ wcount, const uint2* __restrict__ recs, uint32_t cap) {
  __shared__ uint32_t chs[4*RJ_LEV];
  __shared__ int bmax;
  const int tid = threadIdx.x;
  if (tid < 4*RJ_LEV) chs[tid] = g_chains[2*KN_LEV + tid];
  if (tid == 0) bmax = 1;
  __syncthreads();
  uint32_t n = *wcount; if (n > cap) n = cap;
  const float ll5 = g_ll5, aa5 = g_aa5, bb5 = g_bb5, inva5 = g_inva5, vr5 = g_vr5;
  int mymax = 1;
  for (uint32_t gi = blockIdx.x * 256u + tid; gi < n; gi += gridDim.x * 256u) {
    uint2 r = recs[gi];
    const uint32_t m = r.x; const float lamr = __uint_as_float(r.y);
    float ll, aa, bbv, inva, vr;
    if (lamr == 1e5f) { ll = ll5; aa = aa5; bbv = bb5; inva = inva5; vr = vr5; }
    else rej_constants(lamr, &ll, &aa, &bbv, &inva, &vr);
    int jf = RJ_LEV;
#pragma unroll 1
    for (int j = 1; j < RJ_LEV; ++j) {
      float uu = u01_from_key(chs[4*j], chs[4*j+1], m) - 0.5f;
      float vv = u01_from_key(chs[4*j+2], chs[4*j+3], m);
      float kk;
      if (rej_iter(lamr, ll, aa, bbv, inva, vr, uu, vv, &kk)) { jf = j + 1; break; }
    }
    mymax = max(mymax, jf);
  }
  for (int off = 32; off > 0; off >>= 1) mymax = max(mymax, __shfl_down(mymax, off, 64));
  if ((tid & 63) == 0) atomicMax(&bmax, mymax);
  __syncthreads();
  if (tid == 0) atomicMax(&g_T, bmax);
}

// sample: dense branch-free knuth levels 0..2 for ALL elements, then STAGED-DENSE
// tail (3 levels per stage, re-compacted; all live entries share jstart so level
// keys stay wave-uniform), backward-from-T rejection, fused einsum.
__global__ void __launch_bounds__(256)
sample_kernel(const float* __restrict__ photon, const float* __restrict__ sbr,
              const int* __restrict__ bins, const float* __restrict__ w,
              float* __restrict__ out) {
  __shared__ uint32_t ch[CH_N];
  __shared__ float lamS[N_T];
  __shared__ float cntS[N_T];
  __shared__ uint16_t rejL[N_T];
  __shared__ uint16_t listA[N_T], listB[N_T];
  __shared__ float    lpA[N_T], lpB[N_T];
  __shared__ uint32_t nA, nB, nRej;
  __shared__ float wred[4][KCH];
  const int b = blockIdx.x, tid = threadIdx.x;
  if (tid < CH_N) ch[tid] = g_chains[tid];
  if (tid == 0) { nA = 0u; nB = 0u; nRej = 0u; }
  __syncthreads();

  const float ph = photon[b], sb = sbr[b];
  const int   shift = bins[b] & (N_T - 1);
  const double scale = (double)ph / g_area;
  const float  r1f = ph / sb;
  const double amb = (double)r1f * (1.0 / 1024.0);
  const uint32_t mbase = (uint32_t)b << 10;

  // phase 1: lam + dense knuth levels 0..DENSE_L-1, branch-free
  for (int i2 = 0; i2 < 4; ++i2) {
    const int t   = tid + (i2 << 8);
    const int src = (t - shift) & (N_T - 1);
    const float lam = (float)(scale * g_conv2[src] + amb);
    lamS[t] = lam;
    const bool kn = (lam < 10.0f);
    const float neg = -lam;
    const uint32_t m = mbase + (uint32_t)t;
    float lp = 0.0f; int k = 0;
#pragma unroll
    for (int j = 0; j < DENSE_L; ++j) {
      k += (lp > neg) ? 1 : 0;
      float u = u01_from_key(ch[2*j], ch[2*j+1], m);
      lp += __logf(u);
    }
    const bool alive = (lp > neg);
    if (kn && !alive) cntS[t] = (float)(k - 1);
    bool srv = kn && alive;                 // survivors all have k == DENSE_L
    uint32_t sS = wave_append(srv, &nA);
    if (srv) { listA[sS] = (uint16_t)t; lpA[sS] = lp; }
    uint32_t sR = wave_append(!kn, &nRej);
    if (!kn) rejL[sR] = (uint16_t)t;
  }

  // phase 2: STAGED-DENSE tail. Each stage runs L (=3) levels branch-free for all
  // live entries (uniform jstart), writes finished counts, re-compacts survivors.
  {
    uint16_t* cur = listA;  float* clp = lpA;  uint32_t* curn = &nA;
    uint16_t* nxt = listB;  float* nlp = lpB;  uint32_t* nxtn = &nB;
    int jstart = DENSE_L;
    while (true) {
      __syncthreads();
      const uint32_t nn = *curn;
      if (nn == 0u) break;
      if (jstart >= KN_LEV) {               // depth cap (P ~ 1e-9): clamp
        for (uint32_t i = tid; i < nn; i += 256) cntS[cur[i]] = (float)(KN_LEV - 1);
        break;
      }
      if (tid == 0) *nxtn = 0u;
      __syncthreads();
      const int L = (jstart + 3 <= KN_LEV) ? 3 : (KN_LEV - jstart);
      const uint32_t nnPad = (nn + 255u) & ~255u;
      for (uint32_t i = tid; i < nnPad; i += 256) {
        const bool active = (i < nn);
        uint16_t t16 = 0; float lp = 0.0f, neg = 1.0f;
        if (active) { t16 = cur[i]; lp = clp[i]; neg = -lamS[t16]; }
        const uint32_t m = mbase + (uint32_t)t16;
        int p = 0;
#pragma unroll 1
        for (int s = 0; s < L; ++s) {       // L wave-uniform; branch-free body
          p += (lp > neg) ? 1 : 0;
          lp += __logf(u01_from_key(ch[2*(jstart+s)], ch[2*(jstart+s)+1], m));
        }
        const bool alive = active && (p == L);
        if (active && !alive) cntS[t16] = (float)(jstart + p - 1);
        uint32_t slot = wave_append(alive, nxtn);
        if (alive) { nxt[slot] = t16; nlp[slot] = lp; }
      }
      { uint16_t* tp = cur; cur = nxt; nxt = tp; }
      { float* tp = clp; clp = nlp; nlp = tp; }
      { uint32_t* tp = curn; curn = nxtn; nxtn = tp; }
      jstart += L;
    }
  }
  __syncthreads();

  // phase 3: rejection elements, exact backward-from-T (last accept in 1..T)
  {
    const int T = g_T;
    const uint32_t nr = nRej;
    for (uint32_t i = tid; i < nr; i += 256) {
      const uint16_t t16 = rejL[i];
      const float lam = lamS[t16];
      const uint32_t m = mbase + (uint32_t)t16;
      float ll, aa, bbv, inva, vr;
      rej_constants(lam, &ll, &aa, &bbv, &inva, &vr);
      float kout = -1.0f;
#pragma unroll 1
      for (int j = T - 1; j >= 0; --j) {
        const uint32_t* c = ch + 2*KN_LEV + 4*j;
        float u = u01_from_key(c[0], c[1], m) - 0.5f;
        float v = u01_from_key(c[2], c[3], m);
        float kf;
        if (rej_iter(lam, ll, aa, bbv, inva, vr, u, v, &kf)) { kout = kf; break; }
      }
      cntS[t16] = kout;
    }
  }
  __syncthreads();

  // fused einsum
  float acc[KCH];
#pragma unroll
  for (int k = 0; k < KCH; ++k) acc[k] = 0.0f;
  for (int i2 = 0; i2 < 4; ++i2) {
    const int t = tid + (i2 << 8);
    const float c = cntS[t];
#pragma unroll
    for (int k = 0; k < KCH; ++k) acc[k] += c * w[k * N_T + t];
  }
  const int lane = tid & 63, wv = tid >> 6;
#pragma unroll
  for (int k = 0; k < KCH; ++k) {
    float v = acc[k];
    for (int off = 32; off > 0; off >>= 1) v += __shfl_down(v, off, 64);
    if (lane == 0) wred[wv][k] = v;
  }
  __syncthreads();
  if (tid < KCH)
    out[b * KCH + tid] = wred[0][tid] + wred[1][tid] + wred[2][tid] + wred[3][tid];
}

extern "C" void kernel_launch(void* const* d_in, const int* in_sizes, int n_in,
                              void* d_out, int out_size, void* d_ws, size_t ws_size,
                              hipStream_t stream) {
  (void)n_in; (void)out_size;
  const float* illum  = (const float*)d_in[0];
  const float* photon = (const float*)d_in[1];
  const float* sbr    = (const float*)d_in[2];
  const float* irf    = (const float*)d_in[3];
  const float* w      = (const float*)d_in[4];
  const int*   bins   = (const int*)d_in[5];
  float* out = (float*)d_out;
  const int B = in_sizes[1];

  uint32_t* wcount = (uint32_t*)d_ws;
  uint2*    recs   = (uint2*)((char*)d_ws + 16);
  uint32_t  cap    = (ws_size > 16) ? (uint32_t)((ws_size - 16) / sizeof(uint2)) : 0u;

  pre1_kernel<<<8, 128, 0, stream>>>(illum, irf);
  pre2_kernel<<<9, 128, 0, stream>>>(irf, wcount);
  t1_kernel<<<B, 256, 0, stream>>>(photon, sbr, bins, wcount, recs, cap);
  t2_kernel<<<2048, 256, 0, stream>>>(wcount, recs, cap);
  sample_kernel<<<B, 256, 0, stream>>>(photon, sbr, bins, w, out);
}

// Round 10
// 1133.607 us; speedup vs baseline: 1.3626x; 1.1130x over previous
//
#include <hip/hip_runtime.h>
#include <hip/hip_bf16.h>
#include <stdint.h>

#define N_T   1024
#define ROLLC 511
#define KCH   8
#define KN_LEV 48                 // knuth chain depth (max increments)
#define DENSE_L 3                 // branch-free dense knuth levels
#define RJ_LEV 24                 // rejection chain depth (T ~ 11-14)
#define CH_N  (2*KN_LEV + 4*RJ_LEV)

__device__ double   g_inp[N_T];
__device__ double   g_conv2[N_T];
__device__ double   g_area;
__device__ uint32_t g_chains[CH_N];
__device__ int      g_T;
__device__ float    g_ll5, g_aa5, g_bb5, g_inva5, g_vr5;   // rejection constants for lam=1e5

struct TF2 { uint32_t x, y; };

// Threefry-2x32, 20 rounds — matches jax._src.prng.threefry2x32 exactly.
__device__ __forceinline__ TF2 tf2x32(uint32_t k0, uint32_t k1, uint32_t c0, uint32_t c1) {
  uint32_t ks2 = k0 ^ k1 ^ 0x1BD11BDAu;
  uint32_t x0 = c0 + k0, x1 = c1 + k1;
#define TFR(r) { x0 += x1; x1 = (x1 << (r)) | (x1 >> (32 - (r))); x1 ^= x0; }
  TFR(13) TFR(15) TFR(26) TFR(6)
  x0 += k1;  x1 += ks2 + 1u;
  TFR(17) TFR(29) TFR(16) TFR(24)
  x0 += ks2; x1 += k0 + 2u;
  TFR(13) TFR(15) TFR(26) TFR(6)
  x0 += k0;  x1 += k1 + 3u;
  TFR(17) TFR(29) TFR(16) TFR(24)
  x0 += k1;  x1 += ks2 + 4u;
  TFR(13) TFR(15) TFR(26) TFR(6)
  x0 += ks2; x1 += k0 + 5u;
#undef TFR
  return {x0, x1};
}

__device__ __forceinline__ float u01_from_key(uint32_t sk0, uint32_t sk1, uint32_t m) {
  TF2 r = tf2x32(sk0, sk1, 0u, m);
  uint32_t bits = r.x ^ r.y;
  return __uint_as_float((bits >> 9) | 0x3f800000u) - 1.0f;
}

// XLA chlo.lgamma f32 decomposition (Lanczos g=7, n=9), x >= 0.5 path only.
__device__ __forceinline__ float lgamma_xla(float x) {
#pragma clang fp contract(off)
  float z = x - 1.0f;
  float sum = 1.0f;
  sum = sum + 676.5203681218851f     / (z + 1.0f);
  sum = sum + -1259.1392167224028f   / (z + 2.0f);
  sum = sum + 771.32342877765313f    / (z + 3.0f);
  sum = sum + -176.61502916214059f   / (z + 4.0f);
  sum = sum + 12.507343278686905f    / (z + 5.0f);
  sum = sum + -0.13857109526572012f  / (z + 6.0f);
  sum = sum + 9.9843695780195716e-6f / (z + 7.0f);
  sum = sum + 1.5056327351493116e-7f / (z + 8.0f);
  float t = 7.5f + z;
  float log_t = 2.0149030205422647f + log1pf(z / 7.5f);
  return 0.91893853320467274f + (z + 0.5f - t / log_t) * log_t + logf(sum);
}

__device__ __forceinline__ void rej_constants(float lam, float* ll, float* aa, float* bb,
                                              float* inva, float* vr) {
#pragma clang fp contract(off)
  *ll = logf(lam);
  float b = 0.931f + 2.53f * sqrtf(lam);
  float a = -0.059f + 0.02483f * b;
  *bb = b; *aa = a;
  *inva = 1.1239f + 1.1328f / (b - 3.4f);
  *vr = 0.9277f - 3.6224f / (b - 2.0f);
}

// Quick classification: 1 = accept, -1 = definite reject, 0 = ambiguous.
__device__ __forceinline__ int ptrs_quick(float lamr, float aa, float bb, float vr,
                                          float u, float v) {
#pragma clang fp contract(off)
  float us = 0.5f - fabsf(u);
  float kf = floorf((2.0f * aa / us + bb) * u + lamr + 0.43f);
  if ((us >= 0.07f) && (v <= vr)) return 1;
  if ((kf < 0.0f) || ((us < 0.013f) && (v > us))) return -1;
  return 0;
}

// Slow (exact) accept test for ambiguous cases.
__device__ __forceinline__ bool ptrs_slow(float lamr, float ll, float aa, float bb,
                                          float inva, float u, float v) {
#pragma clang fp contract(off)
  float us = 0.5f - fabsf(u);
  float kf = floorf((2.0f * aa / us + bb) * u + lamr + 0.43f);
  float s = logf(v * inva / (aa / (us * us) + bb));
  float t = (-lamr + kf * ll) - lgamma_xla(kf + 1.0f);
  return s <= t;
}

// One full Hormann PTRS iteration (exact).
__device__ __forceinline__ bool rej_iter(float lam, float ll, float aa, float bb,
                                         float inva, float vr, float u, float v, float* kf) {
#pragma clang fp contract(off)
  float us = 0.5f - fabsf(u);
  float k = floorf((2.0f * aa / us + bb) * u + lam + 0.43f);
  *kf = k;
  if ((us >= 0.07f) && (v <= vr)) return true;
  if ((k < 0.0f) || ((us < 0.013f) && (v > us))) return false;
  float s = logf(v * inva / (aa / (us * us) + bb));
  float t = (-lam + k * ll) - lgamma_xla(k + 1.0f);
  return s <= t;
}

// Wave-aggregated append to an LDS counter. All 64 lanes must call.
__device__ __forceinline__ uint32_t wave_append(bool pred, uint32_t* counter) {
  unsigned long long vote = __ballot(pred);
  int lane = threadIdx.x & 63;
  uint32_t base = 0;
  int cnt = __popcll(vote);
  if (cnt) {
    int leader = __ffsll((unsigned long long)vote) - 1;
    if (lane == leader) base = atomicAdd(counter, (uint32_t)cnt);
    base = (uint32_t)__shfl((int)base, leader, 64);
  }
  return base + (uint32_t)__popcll(vote & ((1ull << lane) - 1ull));
}

// pre1: first f64 circular conv (+roll) of relu(illum) with irf -> g_inp. 8 blocks x 128.
__global__ void __launch_bounds__(128)
pre1_kernel(const float* __restrict__ illum, const float* __restrict__ irf) {
  __shared__ double xs[N_T], irfs[N_T];
  const int tid = threadIdx.x;
  for (int i = tid; i < N_T; i += 128) {
    xs[i]   = fmax((double)illum[i], 0.0);
    irfs[i] = (double)irf[i];
  }
  __syncthreads();
  const int t  = blockIdx.x * 128 + tid;
  const int tt = (t + ROLLC) & (N_T - 1);
  double acc = 0.0;
  for (int j = 0; j < N_T; ++j) acc += xs[j] * irfs[(tt - j) & (N_T - 1)];
  g_inp[t] = acc;
}

// pre2: blocks 0-7 second conv (+roll) -> g_conv2; block 8: area, chains, constants, resets.
__global__ void __launch_bounds__(128)
pre2_kernel(const float* __restrict__ irf, uint32_t* __restrict__ wcount) {
  __shared__ double inps[N_T], irfs[N_T];
  const int tid = threadIdx.x;
  if (blockIdx.x < 8) {
    for (int i = tid; i < N_T; i += 128) {
      inps[i] = g_inp[i];
      irfs[i] = (double)irf[i];
    }
    __syncthreads();
    const int t  = blockIdx.x * 128 + tid;
    const int tt = (t + ROLLC) & (N_T - 1);
    double acc = 0.0;
    for (int j = 0; j < N_T; ++j) acc += inps[j] * irfs[(tt - j) & (N_T - 1)];
    g_conv2[t] = acc;
  } else {
    if (tid == 0) {
      g_T = 1;
      wcount[0] = 0u;
      double area = 0.0;
      for (int j = 0; j < N_T; ++j) area += g_inp[j];
      g_area = area;
    } else if (tid == 1) {
      uint32_t r0 = 0u, r1 = 42u;           // knuth chain: rng,sub = split(rng)
      for (int j = 0; j < KN_LEV; ++j) {
        TF2 sub = tf2x32(r0, r1, 0u, 1u);
        TF2 nxt = tf2x32(r0, r1, 0u, 0u);
        g_chains[2*j] = sub.x; g_chains[2*j+1] = sub.y;
        r0 = nxt.x; r1 = nxt.y;
      }
    } else if (tid == 2) {
      uint32_t c0 = 0u, c1 = 42u;           // rejection chain: split(key,3)
      for (int j = 0; j < RJ_LEV; ++j) {
        TF2 nxt = tf2x32(c0, c1, 0u, 0u);
        TF2 s0  = tf2x32(c0, c1, 0u, 1u);
        TF2 s1  = tf2x32(c0, c1, 0u, 2u);
        int base = 2*KN_LEV + 4*j;
        g_chains[base]   = s0.x; g_chains[base+1] = s0.y;
        g_chains[base+2] = s1.x; g_chains[base+3] = s1.y;
        c0 = nxt.x; c1 = nxt.y;
      }
    } else if (tid == 3) {
      float ll, aa, bb, inva, vr;
      rej_constants(1e5f, &ll, &aa, &bb, &inva, &vr);
      g_ll5 = ll; g_aa5 = aa; g_bb5 = bb; g_inva5 = inva; g_vr5 = vr;
    }
  }
}

// t1: dense quick-classify; ambiguous compacted in LDS + slow eval; survivors
// staged in LDS lrec; ONE global atomicAdd per block; coalesced flush.
__global__ void __launch_bounds__(256)
t1_kernel(const float* __restrict__ photon, const float* __restrict__ sbr,
          const int* __restrict__ bins, uint32_t* __restrict__ wcount,
          uint2* __restrict__ recs, uint32_t cap) {
  __shared__ uint2    lrec[N_T];                   // survivors (8KB)
  __shared__ uint32_t amb_m[N_T];                  // ambiguous (4KB)
  __shared__ float    amb_u[N_T], amb_v[N_T], amb_lam[N_T];  // (12KB)
  __shared__ uint32_t lcount, acount, gbase;
  const int b = blockIdx.x, tid = threadIdx.x;
  if (tid == 0) { lcount = 0u; acount = 0u; }
  __syncthreads();

  const float ph = photon[b], sb = sbr[b];
  const int   shift = bins[b] & (N_T - 1);
  const double scale = (double)ph / g_area;
  const float  r1f = ph / sb;
  const double amb = (double)r1f * (1.0 / 1024.0);
  const uint32_t sa0 = g_chains[2*KN_LEV+0], sa1 = g_chains[2*KN_LEV+1];
  const uint32_t sc0 = g_chains[2*KN_LEV+2], sc1 = g_chains[2*KN_LEV+3];
  const float ll5 = g_ll5, aa5 = g_aa5, bb5 = g_bb5, inva5 = g_inva5, vr5 = g_vr5;
  const uint32_t mbase = (uint32_t)b << 10;

  // dense quick classification
  for (int i2 = 0; i2 < 4; ++i2) {
    const int t   = tid + (i2 << 8);
    const int src = (t - shift) & (N_T - 1);
    const float lam = (float)(scale * g_conv2[src] + amb);
    float lamr, aa, bbv, vr;
    if (lam < 10.0f) { lamr = 1e5f; aa = aa5; bbv = bb5; vr = vr5; }
    else {
#pragma clang fp contract(off)
      lamr = lam;
      float b2 = 0.931f + 2.53f * sqrtf(lam);
      bbv = b2; aa = -0.059f + 0.02483f * b2;
      vr = 0.9277f - 3.6224f / (b2 - 2.0f);
    }
    const uint32_t m = mbase + (uint32_t)t;
    float u = u01_from_key(sa0, sa1, m) - 0.5f;
    float v = u01_from_key(sc0, sc1, m);
    int cls = ptrs_quick(lamr, aa, bbv, vr, u, v);
    bool surv = (cls < 0);
    bool ambg = (cls == 0);
    uint32_t sS = wave_append(surv, &lcount);
    if (surv) lrec[sS] = make_uint2(m, __float_as_uint(lamr));
    uint32_t sA = wave_append(ambg, &acount);
    if (ambg) { amb_m[sA] = m; amb_u[sA] = u; amb_v[sA] = v; amb_lam[sA] = lamr; }
  }
  __syncthreads();

  // compacted slow eval (exact) for ambiguous
  const uint32_t na = acount;
  const uint32_t naPad = (na + 255u) & ~255u;
  for (uint32_t i = tid; i < naPad; i += 256) {
    bool active = (i < na);
    bool surv = false;
    uint32_t m = 0; float lamr = 0.f;
    if (active) {
      m = amb_m[i]; lamr = amb_lam[i];
      float u = amb_u[i], v = amb_v[i];
      float ll, aa, bbv, inva;
      if (lamr == 1e5f) { ll = ll5; aa = aa5; bbv = bb5; inva = inva5; }
      else {
#pragma clang fp contract(off)
        float b2 = 0.931f + 2.53f * sqrtf(lamr);
        bbv = b2; aa = -0.059f + 0.02483f * b2;
        ll = logf(lamr);
        inva = 1.1239f + 1.1328f / (b2 - 3.4f);
      }
      surv = !ptrs_slow(lamr, ll, aa, bbv, inva, u, v);
    }
    uint32_t sS = wave_append(surv, &lcount);
    if (surv) lrec[sS] = make_uint2(m, __float_as_uint(lamr));
  }
  __syncthreads();

  // ONE global atomic per block, then coalesced flush
  if (tid == 0) gbase = atomicAdd(wcount, lcount);
  __syncthreads();
  const uint32_t lc = lcount, base = gbase;
  for (uint32_t i = tid; i < lc; i += 256) {
    const uint32_t g = base + i;
    uint2 r = lrec[i];
    if (g < cap) {
      recs[g] = r;
    } else {  // ws overflow (not expected): resolve exactly inline
      const uint32_t m = r.x; const float lamr = __uint_as_float(r.y);
      float ll, aaf, bbf, invaf, vrf;
      if (lamr == 1e5f) { ll = ll5; aaf = aa5; bbf = bb5; invaf = inva5; vrf = vr5; }
      else rej_constants(lamr, &ll, &aaf, &bbf, &invaf, &vrf);
      int jf = RJ_LEV;
#pragma unroll 1
      for (int j = 1; j < RJ_LEV; ++j) {
        const uint32_t* c = g_chains + 2*KN_LEV + 4*j;
        float uu = u01_from_key(c[0], c[1], m) - 0.5f;
        float vv = u01_from_key(c[2], c[3], m);
        float kk;
        if (rej_iter(lamr, ll, aaf, bbf, invaf, vrf, uu, vv, &kk)) { jf = j + 1; break; }
      }
      atomicMax(&g_T, jf);
    }
  }
}

// t2: levels 2+ for compacted survivors only; global T via atomicMax.
__global__ void __launch_bounds__(256)
t2_kernel(const uint32_t* __restrict__ wcount, const uint2* __restrict__ recs, uint32_t cap) {
  __shared__ uint32_t chs[4*RJ_LEV];
  __shared__ int bmax;
  const int tid = threadIdx.x;
  if (tid < 4*RJ_LEV) chs[tid] = g_chains[2*KN_LEV + tid];
  if (tid == 0) bmax = 1;
  __syncthreads();
  uint32_t n = *wcount; if (n > cap) n = cap;
  const float ll5 = g_ll5, aa5 = g_aa5, bb5 = g_bb5, inva5 = g_inva5, vr5 = g_vr5;
  int mymax = 1;
  for (uint32_t gi = blockIdx.x * 256u + tid; gi < n; gi += gridDim.x * 256u) {
    uint2 r = recs[gi];
    const uint32_t m = r.x; const float lamr = __uint_as_float(r.y);
    float ll, aa, bbv, inva, vr;
    if (lamr == 1e5f) { ll = ll5; aa = aa5; bbv = bb5; inva = inva5; vr = vr5; }
    else rej_constants(lamr, &ll, &aa, &bbv, &inva, &vr);
    int jf = RJ_LEV;
#pragma unroll 1
    for (int j = 1; j < RJ_LEV; ++j) {
      float uu = u01_from_key(chs[4*j], chs[4*j+1], m) - 0.5f;
      float vv = u01_from_key(chs[4*j+2], chs[4*j+3], m);
      float kk;
      if (rej_iter(lamr, ll, aa, bbv, inva, vr, uu, vv, &kk)) { jf = j + 1; break; }
    }
    mymax = max(mymax, jf);
  }
  for (int off = 32; off > 0; off >>= 1) mymax = max(mymax, __shfl_down(mymax, off, 64));
  if ((tid & 63) == 0) atomicMax(&bmax, mymax);
  __syncthreads();
  if (tid == 0) atomicMax(&g_T, bmax);
}

// sample: dense branch-free knuth levels 0..DENSE_L-1 for ALL elements, one
// compaction, per-thread tail for the ~11% survivors, backward-from-T rejection,
// fused einsum. (Best-measured configuration, r6.)
__global__ void __launch_bounds__(256)
sample_kernel(const float* __restrict__ photon, const float* __restrict__ sbr,
              const int* __restrict__ bins, const float* __restrict__ w,
              float* __restrict__ out) {
  __shared__ uint32_t ch[CH_N];
  __shared__ float lamS[N_T];
  __shared__ float cntS[N_T];
  __shared__ uint16_t rejL[N_T];
  __shared__ uint16_t surPK[N_T];     // (k<<10)|t
  __shared__ float    surLP[N_T];
  __shared__ uint32_t nSur, nRej;
  __shared__ float wred[4][KCH];
  const int b = blockIdx.x, tid = threadIdx.x;
  if (tid < CH_N) ch[tid] = g_chains[tid];
  if (tid == 0) { nSur = 0u; nRej = 0u; }
  __syncthreads();

  const float ph = photon[b], sb = sbr[b];
  const int   shift = bins[b] & (N_T - 1);
  const double scale = (double)ph / g_area;
  const float  r1f = ph / sb;
  const double amb = (double)r1f * (1.0 / 1024.0);
  const uint32_t mbase = (uint32_t)b << 10;

  // phase 1: lam + dense knuth levels 0..DENSE_L-1, branch-free
  for (int i2 = 0; i2 < 4; ++i2) {
    const int t   = tid + (i2 << 8);
    const int src = (t - shift) & (N_T - 1);
    const float lam = (float)(scale * g_conv2[src] + amb);
    lamS[t] = lam;
    const bool kn = (lam < 10.0f);
    const float neg = -lam;
    const uint32_t m = mbase + (uint32_t)t;
    float lp = 0.0f; int k = 0;
#pragma unroll
    for (int j = 0; j < DENSE_L; ++j) {
      k += (lp > neg) ? 1 : 0;
      float u = u01_from_key(ch[2*j], ch[2*j+1], m);
      lp += __logf(u);
    }
    const bool alive = (lp > neg);
    if (kn && !alive) cntS[t] = (float)(k - 1);
    bool srv = kn && alive;
    uint32_t sS = wave_append(srv, &nSur);
    if (srv) { surPK[sS] = (uint16_t)((k << 10) | t); surLP[sS] = lp; }
    uint32_t sR = wave_append(!kn, &nRej);
    if (!kn) rejL[sR] = (uint16_t)t;
  }
  __syncthreads();

  // phase 2: knuth tail for survivors (compacted, per-thread early-break)
  {
    const uint32_t nS = nSur;
    for (uint32_t i = tid; i < nS; i += 256) {
      const uint16_t pk = surPK[i];
      const uint16_t t16 = pk & 1023u;
      int k = pk >> 10;
      float lp = surLP[i];
      const float neg = -lamS[t16];
      const uint32_t m = mbase + (uint32_t)t16;
      int j = DENSE_L;
#pragma unroll 1
      while ((lp > neg) && (j < KN_LEV)) {
        ++k;
        lp += __logf(u01_from_key(ch[2*j], ch[2*j+1], m));
        ++j;
      }
      cntS[t16] = (float)(k - 1);
    }
  }

  // phase 3: rejection elements, exact backward-from-T (last accept in 1..T)
  {
    const int T = g_T;
    const uint32_t nr = nRej;
    for (uint32_t i = tid; i < nr; i += 256) {
      const uint16_t t16 = rejL[i];
      const float lam = lamS[t16];
      const uint32_t m = mbase + (uint32_t)t16;
      float ll, aa, bbv, inva, vr;
      rej_constants(lam, &ll, &aa, &bbv, &inva, &vr);
      float kout = -1.0f;
#pragma unroll 1
      for (int j = T - 1; j >= 0; --j) {
        const uint32_t* c = ch + 2*KN_LEV + 4*j;
        float u = u01_from_key(c[0], c[1], m) - 0.5f;
        float v = u01_from_key(c[2], c[3], m);
        float kf;
        if (rej_iter(lam, ll, aa, bbv, inva, vr, u, v, &kf)) { kout = kf; break; }
      }
      cntS[t16] = kout;
    }
  }
  __syncthreads();

  // fused einsum
  float acc[KCH];
#pragma unroll
  for (int k = 0; k < KCH; ++k) acc[k] = 0.0f;
  for (int i2 = 0; i2 < 4; ++i2) {
    const int t = tid + (i2 << 8);
    const float c = cntS[t];
#pragma unroll
    for (int k = 0; k < KCH; ++k) acc[k] += c * w[k * N_T + t];
  }
  const int lane = tid & 63, wv = tid >> 6;
#pragma unroll
  for (int k = 0; k < KCH; ++k) {
    float v = acc[k];
    for (int off = 32; off > 0; off >>= 1) v += __shfl_down(v, off, 64);
    if (lane == 0) wred[wv][k] = v;
  }
  __syncthreads();
  if (tid < KCH)
    out[b * KCH + tid] = wred[0][tid] + wred[1][tid] + wred[2][tid] + wred[3][tid];
}

extern "C" void kernel_launch(void* const* d_in, const int* in_sizes, int n_in,
                              void* d_out, int out_size, void* d_ws, size_t ws_size,
                              hipStream_t stream) {
  (void)n_in; (void)out_size;
  const float* illum  = (const float*)d_in[0];
  const float* photon = (const float*)d_in[1];
  const float* sbr    = (const float*)d_in[2];
  const float* irf    = (const float*)d_in[3];
  const float* w      = (const float*)d_in[4];
  const int*   bins   = (const int*)d_in[5];
  float* out = (float*)d_out;
  const int B = in_sizes[1];

  uint32_t* wcount = (uint32_t*)d_ws;
  uint2*    recs   = (uint2*)((char*)d_ws + 16);
  uint32_t  cap    = (ws_size > 16) ? (uint32_t)((ws_size - 16) / sizeof(uint2)) : 0u;

  pre1_kernel<<<8, 128, 0, stream>>>(illum, irf);
  pre2_kernel<<<9, 128, 0, stream>>>(irf, wcount);
  t1_kernel<<<B, 256, 0, stream>>>(photon, sbr, bins, wcount, recs, cap);
  t2_kernel<<<2048, 256, 0, stream>>>(wcount, recs, cap);
  sample_kernel<<<B, 256, 0, stream>>>(photon, sbr, bins, w, out);
}